// Round 10
// baseline (30.404 us; speedup 1.0000x reference)
//
#include <hip/hip_runtime.h>
#include <hip/hip_bf16.h>
#include <math.h>

typedef __bf16 bf16;
typedef __bf16 bf16x8 __attribute__((ext_vector_type(8)));
typedef float  f32x4  __attribute__((ext_vector_type(4)));

static constexpr int kTokens = 32768;   // B*S = 8*4096
static constexpr int kH   = 768;
static constexpr int kC   = 64;
static constexpr int kCK  = 64;         // K-chunk (A rows = 256 B, power of 2)
static constexpr int kNQ  = kH / kCK;   // 12 chunks
static constexpr int kTB  = 64;         // tokens per block (4 tiles x 16)
static constexpr int kBW  = 72;         // B lds row stride (144 B: 2-way banks = free)

// ---------- prep (all-coalesced): Wt[n][k]=W_e1^T, row 64 = w_sc = W_ct@W_cd ----------
__global__ __launch_bounds__(256) void prep_kernel(
    const float* __restrict__ W_ct, const float* __restrict__ b_ct,
    const float* __restrict__ W_cd, const float* __restrict__ b_cd,
    const float* __restrict__ W_e1, bf16* __restrict__ Wt,
    float* __restrict__ bsc) {
    __shared__ float t[64][65];
    const int tid = threadIdx.x;
    const int b   = blockIdx.x;
    if (b < 12) {
        const int k0 = b * 64;
        #pragma unroll
        for (int i = 0; i < 16; ++i) {
            int idx = tid + i * 256;
            int k = idx >> 6, n = idx & 63;
            t[k][n] = W_e1[(size_t)(k0 + k) * kC + n];
        }
        __syncthreads();
        #pragma unroll
        for (int i = 0; i < 16; ++i) {
            int idx = tid + i * 256;
            int n = idx >> 6, k = idx & 63;
            Wt[(size_t)n * kH + k0 + k] = (bf16)t[k][n];
        }
    } else if (b < 24) {
        const int k0 = (b - 12) * 64;
        #pragma unroll
        for (int i = 0; i < 16; ++i) {
            int idx = tid + i * 256;
            int k = idx >> 6, c = idx & 63;
            t[k][c] = W_ct[(size_t)(k0 + k) * kC + c];
        }
        __syncthreads();
        if (tid < 64) {
            float s = 0.f;
            #pragma unroll
            for (int c = 0; c < kC; ++c) s += t[tid][c] * W_cd[c];
            Wt[(size_t)kC * kH + k0 + tid] = (bf16)s;
        }
    } else {
        if (tid < 64) {
            float v = b_ct[tid] * W_cd[tid];
            #pragma unroll
            for (int m = 1; m < 64; m <<= 1) v += __shfl_xor(v, m);
            if (tid == 0) bsc[0] = v + b_cd[0];
        }
    }
}

// ---- issue one A-chunk (64 rows x 256 B) via global_load_lds, src pre-swizzled ----
// 8 waves: each wave issues 2 spans (4 rows / 1 KB each). Element (row,k) lands at
// byte row*256 + ((k*4) ^ ((row&7)<<4)); readers apply the same XOR.
__device__ __forceinline__ void issue_a(const float* __restrict__ hs_blk, int q,
                                        float* __restrict__ buf, int wv, int lane) {
    #pragma unroll
    for (int r = 0; r < 2; ++r) {
        const int span   = wv * 2 + r;            // 0..15
        const int absrow = span * 4 + (lane >> 4);
        const int colB   = (lane & 15) * 16;
        const int scol   = colB ^ ((absrow & 7) << 4);
        const char* src  = (const char*)(hs_blk + (size_t)absrow * kH + q * kCK) + scol;
        float* dst = buf + span * 256;            // wave-uniform
        __builtin_amdgcn_global_load_lds(
            (const __attribute__((address_space(1))) void*)src,
            (__attribute__((address_space(3))) void*)dst, 16, 0, 0);
    }
}

// ---------- main: (32768 x 768) @ (768 x 65) bf16 MFMA, 8-wave n-split ----------
// R7 schedule, but each 16-token tile is computed by a PAIR of waves (lower: n=0,1
// + sc; upper: n=2,3) -> 16 waves/CU and 2x independent gl_lds issuers per barrier
// interval. Same bytes, same LDS, same barrier count.
__global__ __launch_bounds__(512, 2) void incong_main(
    const float* __restrict__ hs,      // [kTokens][kH] f32
    const bf16*  __restrict__ Wt,      // [65][kH] bf16
    const float* __restrict__ bsc_p,
    const float* __restrict__ b_e1,
    const float* __restrict__ W_e2,
    const float* __restrict__ b_e2,
    float* __restrict__ out)           // [3][kTokens]
{
    __shared__ float lds_a[2][kTB][kCK];   // 2 x 16 KB, rows 256 B, no pad (swizzled)
    __shared__ bf16  lds_w[65][kBW];       // 9.4 KB
    __shared__ float red[4][16];           // upper->lower ev partials (256 B)

    const int  tid   = threadIdx.x;
    const int  lane  = tid & 63;
    const int  wv    = tid >> 6;       // 0..7
    const int  tile  = wv & 3;         // 16-token tile
    const bool low   = wv < 4;         // lower wave of the pair
    const int  r16   = lane & 15;
    const int  kg    = lane >> 4;      // 0..3

    const int tok0 = blockIdx.x * kTB;
    const float* hs_blk = hs + (size_t)tok0 * kH;

    f32x4 acc0 = (f32x4){0.f,0.f,0.f,0.f};
    f32x4 acc1 = (f32x4){0.f,0.f,0.f,0.f};
    f32x4 acc2 = (f32x4){0.f,0.f,0.f,0.f};      // sc (lower waves only)

    const int      trow  = tile * 16 + r16;
    const unsigned sw    = (unsigned)((r16 & 7) << 4);
    const char*    ab0   = (const char*)&lds_a[0][trow][0];
    const char*    ab1   = (const char*)&lds_a[1][trow][0];

    // B staging coords: 512 thr cover rows 0..63 (1 bf16x8 each); tid<8 add row 64.
    const int brow = tid >> 3, bcol = (tid & 7) * 8;
    const int nr0 = (low ? 0 : 32) + r16;        // B rows for this wave's 2 n-groups
    const int nr1 = nr0 + 16;

    issue_a(hs_blk, 0, &lds_a[0][0][0], wv, lane);     // prologue: A(0) in flight

    for (int q = 0; q < kNQ; ++q) {
        const int pb = q & 1;
        // ---- stage B chunk q (loads then writes; compiler's vmcnt before the
        //      ds_write drains A(q) exactly, leaving A(q+1) outstanding) ----
        {
            bf16x8 v0 = *reinterpret_cast<const bf16x8*>(&Wt[(size_t)brow * kH + q * kCK + bcol]);
            bf16x8 v2;
            if (tid < 8) v2 = *reinterpret_cast<const bf16x8*>(&Wt[(size_t)64 * kH + q * kCK + tid * 8]);
            if (q + 1 < kNQ) issue_a(hs_blk, q + 1, &lds_a[pb ^ 1][0][0], wv, lane);
            *reinterpret_cast<bf16x8*>(&lds_w[brow][bcol]) = v0;
            if (tid < 8) *reinterpret_cast<bf16x8*>(&lds_w[64][tid * 8]) = v2;
        }
        asm volatile("s_waitcnt lgkmcnt(0)" ::: "memory");
        __builtin_amdgcn_s_barrier();
        asm volatile("" ::: "memory");

        // ---- compute chunk q: swizzled A reads + MFMA (wave-uniform n-split) ----
        const char* abase = pb ? ab1 : ab0;
        #pragma unroll
        for (int s = 0; s < 2; ++s) {
            const unsigned o = (unsigned)(s * 128 + kg * 32);
            const f32x4 a0 = *reinterpret_cast<const f32x4*>(abase + (o ^ sw));
            const f32x4 a1 = *reinterpret_cast<const f32x4*>(abase + ((o + 16u) ^ sw));
            bf16x8 af;
            af[0] = (bf16)a0[0]; af[1] = (bf16)a0[1]; af[2] = (bf16)a0[2]; af[3] = (bf16)a0[3];
            af[4] = (bf16)a1[0]; af[5] = (bf16)a1[1]; af[6] = (bf16)a1[2]; af[7] = (bf16)a1[3];
            const bf16x8 bf0 = *reinterpret_cast<const bf16x8*>(&lds_w[nr0][s * 32 + kg * 8]);
            const bf16x8 bf1 = *reinterpret_cast<const bf16x8*>(&lds_w[nr1][s * 32 + kg * 8]);
            acc0 = __builtin_amdgcn_mfma_f32_16x16x32_bf16(af, bf0, acc0, 0, 0, 0);
            acc1 = __builtin_amdgcn_mfma_f32_16x16x32_bf16(af, bf1, acc1, 0, 0, 0);
            if (low) {
                const bf16x8 b4 = *reinterpret_cast<const bf16x8*>(&lds_w[64][s * 32 + kg * 8]);
                acc2 = __builtin_amdgcn_mfma_f32_16x16x32_bf16(af, b4, acc2, 0, 0, 0);
            }
        }
        asm volatile("" ::: "memory");
        __builtin_amdgcn_s_barrier();      // all waves done reading before next overwrite
    }

    // ---- epilogue: this wave's 32 cols; pair combined via red[] ----
    const int cidx0 = (low ? 0 : 32) + r16;
    const int cidx1 = cidx0 + 16;
    const float be0 = b_e1[cidx0], we0 = W_e2[cidx0];
    const float be1 = b_e1[cidx1], we1 = W_e2[cidx1];
    float part[4];
    #pragma unroll
    for (int r = 0; r < 4; ++r)
        part[r] = fmaxf(acc0[r] + be0, 0.f) * we0 + fmaxf(acc1[r] + be1, 0.f) * we1;
    #pragma unroll
    for (int m = 1; m < 16; m <<= 1) {
        #pragma unroll
        for (int r = 0; r < 4; ++r) part[r] += __shfl_xor(part[r], m);
    }
    if (!low && r16 == 0) {
        #pragma unroll
        for (int r = 0; r < 4; ++r) red[tile][kg * 4 + r] = part[r];
    }
    __syncthreads();
    if (low && r16 == 0) {
        const float bsc = bsc_p[0];
        const float be2 = b_e2[0];
        #pragma unroll
        for (int r = 0; r < 4; ++r) {
            const int tok = tok0 + tile * 16 + kg * 4 + r;
            const float sc = acc2[r] + bsc;
            const float ev = part[r] + red[tile][kg * 4 + r] + be2;
            out[tok]               = 1.f / (1.f + __expf(-sc));
            out[kTokens + tok]     = 1.f / (1.f + __expf(-ev));
            out[2 * kTokens + tok] = 1.f / 4096.f;     // mean of softmax == 1/S
        }
    }
}

extern "C" void kernel_launch(void* const* d_in, const int* in_sizes, int n_in,
                              void* d_out, int out_size, void* d_ws, size_t ws_size,
                              hipStream_t stream) {
    const float* hs   = (const float*)d_in[0];
    // d_in[1] = attention_mask (all ones, unused by the reference math)
    const float* W_ct = (const float*)d_in[2];
    const float* b_ct = (const float*)d_in[3];
    const float* W_cd = (const float*)d_in[4];
    const float* b_cd = (const float*)d_in[5];
    const float* W_e1 = (const float*)d_in[6];
    const float* b_e1 = (const float*)d_in[7];
    const float* W_e2 = (const float*)d_in[8];
    const float* b_e2 = (const float*)d_in[9];
    // d_in[10..13] = W_q, b_q, W_k, b_k — unused (surprise is exactly 1/S)

    bf16*  Wt  = (bf16*)d_ws;
    float* bsc = (float*)((char*)d_ws + (size_t)80 * kH * sizeof(bf16));

    prep_kernel<<<25, 256, 0, stream>>>(W_ct, b_ct, W_cd, b_cd, W_e1, Wt, bsc);

    incong_main<<<kTokens / kTB, 512, 0, stream>>>(
        hs, Wt, bsc, b_e1, W_e2, b_e2, (float*)d_out);
}